// Round 7
// baseline (717.047 us; speedup 1.0000x reference)
//
#include <hip/hip_runtime.h>
#include <hip/hip_fp16.h>
#include <math.h>

// ESN: FFT(262144) over 32 cols -> fused(proj -> chunked tanh scan -> out matmul)
//      -> IFFT, REAL part only to d_out as float32 [T,32].
//
// R7: scan proj/state LDS back to float2 (R5/R6's fp16 p.y had ulp=1.0 at
// |y|~1200 -> sin(2y) decorrelated on transition steps -> the 7.6e-4 error;
// R6 proved twiddles were innocent by bit-identical failure). Keeps R6's
// 1-ulp LDS twiddle tables, saturation fast path, fp16 outc, fp16 inverse
// intermediate.

constexpr int TLEN = 262144;   // 2^18 = 512*512
constexpr int NCOL = 32;       // IN == OUT == 32 columns
constexpr int NR = 50;         // reservoir size
constexpr int SCH = 64;        // scan chunk length (4096 chunks)
constexpr int LW = 16;         // scan warmup rows (P(fail) ~ 1e-35)
constexpr int MROWS = SCH + LW;  // 80
constexpr int LST = 51;        // scan LDS row stride in float2
constexpr int FPAD = 9;        // FFT LDS row stride in float2 (8 cols + 1 pad)
constexpr float TWO_PI = 6.28318530717958647692f;

__device__ __forceinline__ unsigned rev9(unsigned x) { return __brev(x) >> 23; }

__device__ __forceinline__ float2 cmul(float2 a, float2 b) {
  return make_float2(a.x * b.x - a.y * b.y, a.x * b.y + a.y * b.x);
}

// Build 512-entry twiddle table: tw[k] = e^{SIGN*2pi*i*k*step}, 1-ulp OCML.
template <int SIGN>
__device__ __forceinline__ void build_tw(float2* tw, float step, int tid) {
  for (int k = tid; k < 512; k += 256) {
    float s, c;
    __sincosf((float)SIGN * TWO_PI * (float)k * step, &s, &c);
    tw[k] = make_float2(c, s);
  }
}

// In-LDS 512-point radix-2 DIT FFT on 8 interleaved columns, table twiddles.
// lds[512][FPAD], input bit-reversed (rev9) on load. 256 threads.
__device__ __forceinline__ void fft512(float2 (*lds)[FPAD], const float2* twc,
                                       int tid) {
  const int cl = tid & 7;
  const int bb = tid >> 3;
#pragma unroll
  for (int s = 1; s <= 9; ++s) {
    const int half = 1 << (s - 1);
#pragma unroll
    for (int i = 0; i < 8; ++i) {
      const int b = bb + (i << 5);            // butterfly slot 0..255
      const int j = b & (half - 1);
      const int g = b >> (s - 1);
      const int i1 = (g << s) + j;
      const int i2 = i1 + half;
      float2 a = lds[i1][cl];
      float2 c = lds[i2][cl];
      const float2 t = cmul(c, twc[j << (9 - s)]);  // exact table index
      lds[i1][cl] = make_float2(a.x + t.x, a.y + t.y);
      lds[i2][cl] = make_float2(a.x - t.x, a.y - t.y);
    }
    __syncthreads();
  }
}

// Pass A: input index n = nL + 512*nH; for block nL, FFT over nH -> kL,
// apply twiddle e^{SIGN*2pi*i*nL*kL/T} = twc[m>>9]*twf[m&511] (m = nL*kL),
// store I[kL][nL] at row (kL*512+nL).
// INM: 0 = real f32 input (fwd, X); 1 = half2 complex input (inv, outc).
// OUTM: 0 = float2 out; 1 = half2 out (inverse intermediate).
template <int SIGN, int INM, int OUTM>
__global__ __launch_bounds__(256) void fft_passA(const void* __restrict__ vin,
                                                 void* __restrict__ vout) {
  __shared__ float2 lds[512][FPAD];
  __shared__ float2 twc[512], twf[512];
  const int nL = blockIdx.x;
  const int cg = blockIdx.y;
  const int tid = threadIdx.x;
  const int cl = tid & 7;
  const int rg = tid >> 3;
  const int cglob = cg * 8 + cl;
  build_tw<SIGN>(twc, 1.0f / 512.0f, tid);
  build_tw<SIGN>(twf, 1.0f / 262144.0f, tid);
#pragma unroll
  for (int i = 0; i < 16; ++i) {
    const int nH = rg + (i << 5);
    const size_t gidx = (size_t)(nL + (nH << 9)) * NCOL + cglob;
    float2 v;
    if (INM == 0) {
      v = make_float2(((const float*)vin)[gidx], 0.0f);
    } else {
      v = __half22float2(((const __half2*)vin)[gidx]);
    }
    lds[rev9(nH)][cl] = v;
  }
  __syncthreads();
  fft512(lds, twc, tid);
#pragma unroll
  for (int i = 0; i < 16; ++i) {
    const int kL = rg + (i << 5);
    const int m = nL * kL;                       // < 2^18, exact
    const float2 tw = cmul(twc[m >> 9], twf[m & 511]);
    const float2 w = cmul(lds[kL][cl], tw);
    const size_t o = (size_t)(kL * 512 + nL) * NCOL + cglob;
    if (OUTM == 0) ((float2*)vout)[o] = w;
    else           ((__half2*)vout)[o] = __floats2half2_rn(w.x, w.y);
  }
}

// Pass B: for block kL, FFT over nL (rows kL*512+nL) -> kH.
// OUTM 0 (forward): store IN-PLACE at row (kL*512+kH) -> digit-swapped layout
//   (safe: block reads all 512 rows into LDS before storing).
// OUTM 1 (inverse): store real part * 1/T, natural order, float [T,32].
// INM: 0 = float2 rows, 1 = half2 rows.
template <int SIGN, int INM, int OUTM>
__global__ __launch_bounds__(256) void fft_passB(void* __restrict__ vbuf,
                                                 float* __restrict__ rout) {
  __shared__ float2 lds[512][FPAD];
  __shared__ float2 twc[512];
  const int kL = blockIdx.x;
  const int cg = blockIdx.y;
  const int tid = threadIdx.x;
  const int cl = tid & 7;
  const int rg = tid >> 3;
  const int cglob = cg * 8 + cl;
  build_tw<SIGN>(twc, 1.0f / 512.0f, tid);
#pragma unroll
  for (int i = 0; i < 16; ++i) {
    const int nL = rg + (i << 5);
    const size_t g = (size_t)(kL * 512 + nL) * NCOL + cglob;
    lds[rev9(nL)][cl] = (INM == 0) ? ((const float2*)vbuf)[g]
                                   : __half22float2(((const __half2*)vbuf)[g]);
  }
  __syncthreads();
  fft512(lds, twc, tid);
#pragma unroll
  for (int i = 0; i < 16; ++i) {
    const int kH = rg + (i << 5);
    if (OUTM == 0) {
      ((float2*)vbuf)[(size_t)(kL * 512 + kH) * NCOL + cglob] = lds[kH][cl];
    } else {
      rout[(size_t)(kL + (kH << 9)) * NCOL + cglob] =
          lds[kH][cl].x * (1.0f / 262144.0f);
    }
  }
}

// Fused proj -> scan -> out matmul for one 64-step chunk. 128 threads.
// Xc digit-swapped: row of index t at ((t&511)<<9)|(t>>9).
// Phase A (threads<rows): proj row -> LDS float2 (fp32: p.y ~ N(0,1200) must
//   keep precision mod pi for sin(2y) -- fp16 here was the R5/R6 failure).
// Phase B (wave 0): serial scan. Fast path: ~70% of wave-steps have all
//   lanes |x|>10 where ctanh = sign(x)+0i to fp32 (err<4e-9).
// Phase C: outc = states @ Wout^T (Wout staged in LDS), fp16 store.
__global__ __launch_bounds__(128, 2) void esn_scan_fused(
    const float2* __restrict__ Xc, const float* __restrict__ Win,
    const float* __restrict__ dvec, const float* __restrict__ Wout,
    __half2* __restrict__ outh) {
  __shared__ float2 ps[(MROWS + 1) * LST];   // 81*51*8 = 33,048 B (+1 prefetch pad)
  __shared__ float wo[NCOL * NR];            // 6,400 B
  const int tid = threadIdx.x;
  const int chunk = blockIdx.x;
  const int t0 = chunk * SCH;
  const int W = chunk ? LW : 0;
  const int rows = SCH + W;

  for (int i = tid; i < NCOL * NR; i += 128) wo[i] = Wout[i];

  // Phase A: proj rows [t0-W, t0+SCH) into LDS (float2)
  if (tid < rows) {
    const int t = t0 - W + tid;
    const size_t row = (size_t)(((t & 511) << 9) | (t >> 9));  // digit-swap
    const float4* src = (const float4*)(Xc + row * NCOL);      // 256B aligned
    float2 xc[NCOL];
#pragma unroll
    for (int i = 0; i < NCOL / 2; ++i) {
      float4 v = src[i];
      xc[2 * i] = make_float2(v.x, v.y);
      xc[2 * i + 1] = make_float2(v.z, v.w);
    }
    for (int r = 0; r < NR; ++r) {
      float ar = 0.f, ai = 0.f;
#pragma unroll
      for (int c = 0; c < NCOL; ++c) {
        const float w = Win[r * NCOL + c];  // uniform -> scalar load
        ar = fmaf(w, xc[c].x, ar);
        ai = fmaf(w, xc[c].y, ai);
      }
      ps[tid * LST + r] = make_float2(ar, ai);
    }
  }
  __syncthreads();

  // Phase B: serial scan, wave 0. Prefetch-1 hides the ds_read; in-place is
  // safe by wave lockstep (row i+1 read precedes row i state store).
  if (tid < 64) {
    const int rl = tid < NR ? tid : NR - 1;
    const float d = dvec[rl];
    float sr = 0.f, si = 0.f;
    float2 pn = ps[rl];
    for (int i = 0; i < rows; ++i) {
      const float2 p = pn;
      pn = ps[(i + 1) * LST + rl];  // i+1 <= 80 in-bounds (pad row)
      const float x = fmaf(d, sr, p.x);
      const float y = fmaf(d, si, p.y);
      if (__all(fabsf(x) > 10.0f)) {
        sr = copysignf(1.0f, x);    // ctanh saturated: |err| <= 4e-9
        si = 0.0f;
      } else {
        float x2 = fminf(fmaxf(2.0f * x, -30.0f), 30.0f);
        const float E = __expf(x2);
        const float Ei = __expf(-x2);
        const float sh = 0.5f * (E - Ei);
        const float ch = 0.5f * (E + Ei);
        float s2, c2;
        __sincosf(2.0f * y, &s2, &c2);
        const float inv = __builtin_amdgcn_rcpf(ch + c2);
        sr = sh * inv;
        si = s2 * inv;
      }
      if (tid < NR) ps[i * LST + tid] = make_float2(sr, si);
    }
  }
  __syncthreads();

  // Phase C: outc[t][o] = sum_r s[t][r] * Wout[o][r]; thread -> (row-group,
  // 4-output group); state reads are 8-lane broadcasts, conflict-free.
  const int o0 = (tid & 7) * 4;
  const int g = tid >> 3;  // 0..15
  for (int rg = 0; rg < 4; ++rg) {
    const int rowi = g + rg * 16;  // 0..63
    const float2* srow = &ps[(W + rowi) * LST];
    float ar[4] = {0.f, 0.f, 0.f, 0.f};
    float ai[4] = {0.f, 0.f, 0.f, 0.f};
    for (int r = 0; r < NR; ++r) {
      const float2 s = srow[r];
#pragma unroll
      for (int j = 0; j < 4; ++j) {
        const float w = wo[(o0 + j) * NR + r];
        ar[j] = fmaf(w, s.x, ar[j]);
        ai[j] = fmaf(w, s.y, ai[j]);
      }
    }
#pragma unroll
    for (int j = 0; j < 4; ++j)
      outh[(size_t)(t0 + rowi) * NCOL + o0 + j] = __floats2half2_rn(ar[j], ai[j]);
  }
}

extern "C" void kernel_launch(void* const* d_in, const int* in_sizes, int n_in,
                              void* d_out, int out_size, void* d_ws, size_t ws_size,
                              hipStream_t stream) {
  const float* X = (const float*)d_in[0];      // [T,32] f32
  const float* Win = (const float*)d_in[1];    // [50,32] f32
  const float* dvec = (const float*)d_in[2];   // [50] f32
  const float* Wout = (const float*)d_in[3];   // [32,50] f32

  float2* Wa = (float2*)d_ws;                  // 67,108,864 B complex region
  dim3 fgrid(512, 4);                          // 8 columns per block

  // 1. fwd pass A: X (real f32) -> ws (float2, row kL*512+nL)
  fft_passA<-1, 0, 0><<<fgrid, 256, 0, stream>>>(X, Wa);
  // 2. fwd pass B: ws in-place (Xc digit-swapped, float2)
  fft_passB<-1, 0, 0><<<fgrid, 256, 0, stream>>>(Wa, nullptr);
  // 3. fused proj+scan+out: ws(Xc) -> d_out (outc, fp16 complex [T,32])
  esn_scan_fused<<<TLEN / SCH, 128, 0, stream>>>(Wa, Win, dvec, Wout,
                                                 (__half2*)d_out);
  // 4. inv pass A: d_out (half2 outc) -> ws (half2 intermediate)
  fft_passA<1, 1, 1><<<fgrid, 256, 0, stream>>>(d_out, Wa);
  // 5. inv pass B: ws (half2) -> d_out, REAL part * 1/T, float32 [T,32]
  fft_passB<1, 1, 1><<<fgrid, 256, 0, stream>>>(Wa, (float*)d_out);

  (void)in_sizes; (void)n_in; (void)out_size; (void)ws_size;
}

// Round 8
// 694.579 us; speedup vs baseline: 1.0323x; 1.0323x over previous
//
#include <hip/hip_runtime.h>
#include <hip/hip_fp16.h>
#include <math.h>

// ESN: FFT(262144) over 32 cols -> fused(proj -> chunked tanh scan -> out matmul)
//      -> IFFT, REAL part only to d_out as float32 [T,32].
//
// R8: "piece" intermediate layout ((q*512+kA)*8+c8, q = nH*4+cg) makes pass-A
// stores contiguous and leaves Xc in NATURAL order after in-place pass B
// (row = k: addr8 = (k>>9)*2048 + (c>>3)*512 + (k&511), elem + (c&7)).
// Scan phase A is now a cooperative coalesced load + per-thread proj.
// HW v_sin/v_cos twiddles (R5==R6 bit-identity proved twiddle source is
// output-invariant); XOR bank swizzle on unpadded [512][8] FFT tile.

constexpr int TLEN = 262144;   // 2^18 = 512*512
constexpr int NCOL = 32;       // IN == OUT == 32 columns
constexpr int NR = 50;         // reservoir size
constexpr int SCH = 64;        // scan chunk length (4096 chunks)
constexpr int LW = 16;         // scan warmup rows
constexpr int MROWS = SCH + LW;  // 80
constexpr int LST = 51;        // scan LDS row stride in float2

__device__ __forceinline__ unsigned rev9(unsigned x) { return __brev(x) >> 23; }

__device__ __forceinline__ float2 cmul(float2 a, float2 b) {
  return make_float2(a.x * b.x - a.y * b.y, a.x * b.y + a.y * b.x);
}

// (cos,sin) of 2*pi*rev via HW trig (v_sin/v_cos take REVOLUTIONS; fract first).
__device__ __forceinline__ float2 cs_rev(float rev) {
  const float r = __builtin_amdgcn_fractf(rev);
  return make_float2(__builtin_amdgcn_cosf(r), __builtin_amdgcn_sinf(r));
}

// LDS column swizzle: breaks the rev9-scatter (rows jump in multiples of 16)
// and the even-stride butterfly patterns on the 16-dword row stride.
__device__ __forceinline__ int sc(int row, int c) {
  return (c ^ (row & 7) ^ ((row >> 4) & 7)) & 7;
}

// In-LDS 512-point radix-2 DIT FFT on 8 swizzled columns. lds[512][8],
// input bit-reversed (rev9) on load. 256 threads: col = tid&7, 8 bfly/thread.
template <int SIGN>
__device__ __forceinline__ void fft512(float2 (*lds)[8], int tid) {
  const int cl = tid & 7;
  const int bb = tid >> 3;
#pragma unroll
  for (int s = 1; s <= 9; ++s) {
    const int half = 1 << (s - 1);
    const float stw = (float)SIGN / (float)(1 << s);
#pragma unroll
    for (int i = 0; i < 8; ++i) {
      const int b = bb + (i << 5);            // butterfly slot 0..255
      const int j = b & (half - 1);
      const int g = b >> (s - 1);
      const int i1 = (g << s) + j;
      const int i2 = i1 + half;
      float2 a = lds[i1][sc(i1, cl)];
      float2 c = lds[i2][sc(i2, cl)];
      const float2 t = cmul(c, cs_rev((float)j * stw));  // j/2^s exact
      lds[i1][sc(i1, cl)] = make_float2(a.x + t.x, a.y + t.y);
      lds[i2][sc(i2, cl)] = make_float2(a.x - t.x, a.y - t.y);
    }
    __syncthreads();
  }
}

// grid: 1-D 2048; decode keeps the 4 cg-siblings of one nL 8/16/24 dispatch
// slots apart (same XCD under %8 round-robin, near in time -> L2 line merge).
__device__ __forceinline__ void decode_bid(int bid, int& nL, int& cg) {
  nL = ((bid >> 5) << 3) | (bid & 7);
  cg = (bid >> 3) & 3;
}

// Pass A: t = nL + 512*nH; block (nL, cg): FFT over nH -> kA, twiddle
// e^{SIGN*2pi*i*nL*kA/T}, store piece ((nL*4+cg)*512 + kA)*8 + cl.
// INM: 0 = real f32 input (fwd X); 1 = half2 complex input (inv outc).
// OUTM: 0 = float2 pieces; 1 = half2 pieces (inverse intermediate).
template <int SIGN, int INM, int OUTM>
__global__ __launch_bounds__(256) void fft_passA(const void* __restrict__ vin,
                                                 void* __restrict__ vout) {
  __shared__ float2 lds[512][8];
  int nL, cg;
  decode_bid(blockIdx.x, nL, cg);
  const int tid = threadIdx.x;
  const int cl = tid & 7;
  const int rg = tid >> 3;
  const int cglob = cg * 8 + cl;
#pragma unroll
  for (int i = 0; i < 16; ++i) {
    const int nH = rg + (i << 5);
    const size_t gidx = (size_t)(nL + (nH << 9)) * NCOL + cglob;
    float2 v;
    if (INM == 0) v = make_float2(((const float*)vin)[gidx], 0.0f);
    else          v = __half22float2(((const __half2*)vin)[gidx]);
    const int row = rev9(nH);
    lds[row][sc(row, cl)] = v;
  }
  __syncthreads();
  fft512<SIGN>(lds, tid);
  const size_t qbase = (size_t)(nL * 4 + cg) * 512;
#pragma unroll
  for (int i = 0; i < 16; ++i) {
    const int kA = rg + (i << 5);
    const float2 v = lds[kA][sc(kA, cl)];
    const float2 cs = cs_rev((float)(nL * kA) * ((float)SIGN / 262144.0f));
    const float2 w = cmul(v, cs);
    const size_t o = (qbase + kA) * 8 + cl;   // contiguous 32 KB per block
    if (OUTM == 0) ((float2*)vout)[o] = w;
    else           ((__half2*)vout)[o] = __floats2half2_rn(w.x, w.y);
  }
}

// Pass B: block (kA, cg): reads pieces (nH*4+cg)*512+kA over nH, FFT -> kB,
// stores IN-PLACE at (kB*4+cg)*512+kA (same row set; all reads precede
// stores) -> full result index k = kA + 512*kB lands in NATURAL order.
// OUTM 0: float2 in-place (fwd Xc). OUTM 1: real part * 1/T -> rout [t][32].
template <int SIGN, int INM, int OUTM>
__global__ __launch_bounds__(256) void fft_passB(void* __restrict__ vbuf,
                                                 float* __restrict__ rout) {
  __shared__ float2 lds[512][8];
  int kA, cg;
  decode_bid(blockIdx.x, kA, cg);
  const int tid = threadIdx.x;
  const int cl = tid & 7;
  const int rg = tid >> 3;
#pragma unroll
  for (int i = 0; i < 16; ++i) {
    const int nH = rg + (i << 5);
    const size_t o = ((size_t)(nH * 4 + cg) * 512 + kA) * 8 + cl;
    const float2 v = (INM == 0) ? ((const float2*)vbuf)[o]
                                : __half22float2(((const __half2*)vbuf)[o]);
    const int row = rev9(nH);
    lds[row][sc(row, cl)] = v;
  }
  __syncthreads();
  fft512<SIGN>(lds, tid);
#pragma unroll
  for (int i = 0; i < 16; ++i) {
    const int kB = rg + (i << 5);
    const float2 v = lds[kB][sc(kB, cl)];
    if (OUTM == 0) {
      ((float2*)vbuf)[((size_t)(kB * 4 + cg) * 512 + kA) * 8 + cl] = v;
    } else {
      rout[(size_t)(kA + (kB << 9)) * NCOL + cg * 8 + cl] =
          v.x * (1.0f / 262144.0f);
    }
  }
}

// s' = ctanh(p + d*s) inner step is inlined in phase B below.
// Fused proj -> scan -> out matmul for one 64-step chunk. 128 threads.
// Xc natural order in piece layout: (k,c) at ((k>>9)*2048+(c>>3)*512+(k&511))*8+(c&7).
__global__ __launch_bounds__(128, 2) void esn_scan_fused(
    const float2* __restrict__ Xc, const float* __restrict__ Win,
    const float* __restrict__ dvec, const float* __restrict__ Wout,
    __half2* __restrict__ outh) {
  __shared__ float2 ps[(MROWS + 1) * LST];   // 81*51*8 = 33,048 B
  __shared__ float wo[NCOL * NR];            // 6,400 B
  const int tid = threadIdx.x;
  const int chunk = blockIdx.x;
  const int t0 = chunk * SCH;
  const int W = chunk ? LW : 0;
  const int rows = SCH + W;

  for (int i = tid; i < NCOL * NR; i += 128) wo[i] = Wout[i];

  // A0: cooperative coalesced load of rows [t0-W, t0+SCH) from piece layout.
  for (int idx = tid; idx < rows * 16; idx += 128) {
    const int r = idx >> 4;
    const int c = (idx & 15) << 1;           // float2 col, even
    const int t = t0 - W + r;
    const size_t a = (((size_t)(t >> 9) * 2048 + ((size_t)(c >> 3) << 9) +
                       (t & 511)) << 3) + (c & 7);
    const float4 v = *(const float4*)(Xc + a);  // 16B aligned (c&7 even)
    ps[r * LST + c]     = make_float2(v.x, v.y);
    ps[r * LST + c + 1] = make_float2(v.z, v.w);
  }
  __syncthreads();

  // A1: per-thread proj of its own row, in place (reads row to regs first;
  // no cross-thread aliasing -> no barrier needed inside).
  if (tid < rows) {
    float2 xc[NCOL];
#pragma unroll
    for (int c = 0; c < NCOL; ++c) xc[c] = ps[tid * LST + c];
    for (int r = 0; r < NR; ++r) {
      float ar = 0.f, ai = 0.f;
#pragma unroll
      for (int c = 0; c < NCOL; ++c) {
        const float w = Win[r * NCOL + c];  // uniform -> scalar load
        ar = fmaf(w, xc[c].x, ar);
        ai = fmaf(w, xc[c].y, ai);
      }
      ps[tid * LST + r] = make_float2(ar, ai);
    }
  }
  __syncthreads();

  // B: serial scan, wave 0. Saturation fast path (sigma(Re p)~1.2e3: ~70%
  // of wave-steps have all 50 lanes |x|>10 -> ctanh = sign(x), err<4e-9).
  // In-place safe by wave lockstep (row i+1 read precedes row i store).
  if (tid < 64) {
    const int rl = tid < NR ? tid : NR - 1;
    const float d = dvec[rl];
    float sr = 0.f, si = 0.f;
    float2 pn = ps[rl];
    for (int i = 0; i < rows; ++i) {
      const float2 p = pn;
      pn = ps[(i + 1) * LST + rl];  // i+1 <= 80, in-bounds (81 rows)
      const float x = fmaf(d, sr, p.x);
      const float y = fmaf(d, si, p.y);
      if (__all(fabsf(x) > 10.0f)) {
        sr = copysignf(1.0f, x);
        si = 0.0f;
      } else {
        float x2 = fminf(fmaxf(2.0f * x, -30.0f), 30.0f);
        const float E = __expf(x2);
        const float Ei = __expf(-x2);
        const float sh = 0.5f * (E - Ei);
        const float ch = 0.5f * (E + Ei);
        float s2, c2;
        __sincosf(2.0f * y, &s2, &c2);
        const float inv = __builtin_amdgcn_rcpf(ch + c2);
        sr = sh * inv;
        si = s2 * inv;
      }
      if (tid < NR) ps[i * LST + tid] = make_float2(sr, si);
    }
  }
  __syncthreads();

  // C: outc[t][o] = sum_r s[t][r]*Wout[o][r]; 8-lane row broadcast, fp16 out.
  const int o0 = (tid & 7) * 4;
  const int g = tid >> 3;  // 0..15
  for (int rg = 0; rg < 4; ++rg) {
    const int rowi = g + rg * 16;  // 0..63
    const float2* srow = &ps[(W + rowi) * LST];
    float ar[4] = {0.f, 0.f, 0.f, 0.f};
    float ai[4] = {0.f, 0.f, 0.f, 0.f};
    for (int r = 0; r < NR; ++r) {
      const float2 s = srow[r];
#pragma unroll
      for (int j = 0; j < 4; ++j) {
        const float w = wo[(o0 + j) * NR + r];
        ar[j] = fmaf(w, s.x, ar[j]);
        ai[j] = fmaf(w, s.y, ai[j]);
      }
    }
#pragma unroll
    for (int j = 0; j < 4; ++j)
      outh[(size_t)(t0 + rowi) * NCOL + o0 + j] = __floats2half2_rn(ar[j], ai[j]);
  }
}

extern "C" void kernel_launch(void* const* d_in, const int* in_sizes, int n_in,
                              void* d_out, int out_size, void* d_ws, size_t ws_size,
                              hipStream_t stream) {
  const float* X = (const float*)d_in[0];      // [T,32] f32
  const float* Win = (const float*)d_in[1];    // [50,32] f32
  const float* dvec = (const float*)d_in[2];   // [50] f32
  const float* Wout = (const float*)d_in[3];   // [32,50] f32

  float2* Wa = (float2*)d_ws;                  // 67 MB complex region

  // 1. fwd pass A: X (f32) -> ws (float2 pieces)
  fft_passA<-1, 0, 0><<<2048, 256, 0, stream>>>(X, Wa);
  // 2. fwd pass B: ws in-place -> Xc, NATURAL order (piece layout)
  fft_passB<-1, 0, 0><<<2048, 256, 0, stream>>>(Wa, nullptr);
  // 3. fused proj+scan+out: ws(Xc) -> d_out (outc, fp16 complex [T,32])
  esn_scan_fused<<<TLEN / SCH, 128, 0, stream>>>(Wa, Win, dvec, Wout,
                                                 (__half2*)d_out);
  // 4. inv pass A: d_out (half2 outc) -> ws (half2 pieces)
  fft_passA<1, 1, 1><<<2048, 256, 0, stream>>>(d_out, Wa);
  // 5. inv pass B: ws (half2 pieces) -> d_out, REAL * 1/T, f32 [T,32]
  fft_passB<1, 1, 1><<<2048, 256, 0, stream>>>(Wa, (float*)d_out);

  (void)in_sizes; (void)n_in; (void)out_size; (void)ws_size;
}